// Round 1
// 74.945 us; speedup vs baseline: 1.0720x; 1.0720x over previous
//
#include <hip/hip_runtime.h>
#include <math.h>

#define NN 32
#define TT 1024
#define ROWS 16
#define PAIRS (TT / ROWS / 2)   // 32 pair-blocks per n; pair tile p with tile 63-p
#define TCUT 40.0f              // drop terms with a_{i-1} - a_j > 40 (rel err < e^-24)

__global__ __launch_bounds__(256) void gmsm_kernel(
    const float* __restrict__ time_, const float* __restrict__ loc,
    const float* __restrict__ mu0p, const float* __restrict__ logstd0p,
    const float* __restrict__ cdp, const float* __restrict__ slsp,
    float* __restrict__ out)
{
    const int n = blockIdx.x / PAIRS;
    const int p = blockIdx.x % PAIRS;

    const int loTile = p * ROWS;              // rows [loTile, loTile+ROWS)
    const int hiTile = TT - (p + 1) * ROWS;   // rows [hiTile, hiTile+ROWS)
    const int jmax   = hiTile + ROWS;         // largest index touched + 1
    const int loMax  = loTile + ROWS;

    __shared__ float sa[TT];          // a_j = t_j / softplus(coeff_decay)
    __shared__ float sx[TT];          // loc.x * sqrt(0.5*exp(-2*sls))
    __shared__ float sy[TT];
    __shared__ float se[TT + 544];    // [0,TT): e_j vs baseHi; [TT,TT+loMax): e_j vs baseLo

    const float LOG2PI = 1.8378770664093453f;
    const float cd  = cdp[0];
    const float sls = slsp[0];
    const float inv_sp = 1.0f / logf(1.0f + expf(cd));   // 1/softplus
    const float half_inv2 = 0.5f * expf(-2.0f * sls);    // -cc
    const float cs = sqrtf(half_inv2);                   // coord prescale: dx'^2+dy'^2 = -cc*r2
    const float Cp = -(2.0f * sls + LOG2PI);

    const int tid = threadIdx.x;
    for (int j = tid; j < jmax; j += 256) {
        sa[j] = time_[n * TT + j] * inv_sp;
        float2 l = ((const float2*)loc)[n * TT + j];
        sx[j] = l.x * cs;
        sy[j] = l.y * cs;
    }
    __syncthreads();

    // per-tile bases; the exp(base - a_{i-1}) scale cancels in log(s1)-log(s2)
    const float baseLo = sa[loMax - 1];
    const float baseHi = sa[jmax - 1];
    for (int j = tid; j < jmax; j += 256) {
        const float a = sa[j];
        se[j] = __expf(a - baseHi);
        if (j < loMax) se[TT + j] = __expf(a - baseLo);
    }
    __syncthreads();

    const int wave = tid >> 6;
    const int lane = tid & 63;

    // two groups of 4 consecutive rows per wave (low tile, high tile)
    for (int g = 0; g < 2; ++g) {
        const int i0   = (g == 0 ? loTile : hiTile) + 4 * wave;
        const int eoff = (g == 0) ? TT : 0;

        float xr[4], yr[4];
        #pragma unroll
        for (int r = 0; r < 4; ++r) { xr[r] = sx[i0 + r]; yr[r] = sy[i0 + r]; }

        // truncation window start: first j with sa[j] >= sa[i0-1] - TCUT
        int jlo = 0;
        if (i0 > 64) {
            const float thresh = sa[i0 - 1] - TCUT;
            int lo = 0, hi = i0;
            while (lo < hi) {
                const int mid = (lo + hi) >> 1;
                if (sa[mid] < thresh) lo = mid + 1; else hi = mid;
            }
            jlo = lo;   // jlo <= i0-1 guaranteed (sa[i0-1] >= thresh)
        }

        float s1[4] = {0.f, 0.f, 0.f, 0.f};
        float s2[4] = {0.f, 0.f, 0.f, 0.f};

        // bulk: j in [jlo, i0), shared by all 4 rows
        for (int j = jlo + lane; j < i0; j += 64) {
            const float ej = se[eoff + j];
            const float xj = sx[j];
            const float yj = sy[j];
            #pragma unroll
            for (int r = 0; r < 4; ++r) {
                const float dx = xj - xr[r];
                const float dy = yj - yr[r];
                const float r2 = fmaf(dx, dx, dy * dy);
                s1[r] = fmaf(ej, __expf(-r2), s1[r]);
                s2[r] += ej;
            }
        }
        // tail: j in [i0, i0+3); row r additionally takes j < i0+r
        if (lane < 3) {
            const int jt = i0 + lane;
            const float ej = se[eoff + jt];
            const float xj = sx[jt];
            const float yj = sy[jt];
            #pragma unroll
            for (int r = 1; r < 4; ++r) {
                if (lane < r) {
                    const float dx = xj - xr[r];
                    const float dy = yj - yr[r];
                    const float r2 = fmaf(dx, dx, dy * dy);
                    s1[r] = fmaf(ej, __expf(-r2), s1[r]);
                    s2[r] += ej;
                }
            }
        }

        #pragma unroll
        for (int off = 1; off < 64; off <<= 1) {
            #pragma unroll
            for (int r = 0; r < 4; ++r) {
                s1[r] += __shfl_xor(s1[r], off, 64);
                s2[r] += __shfl_xor(s2[r], off, 64);
            }
        }

        if (lane == 0) {
            #pragma unroll
            for (int r = 0; r < 4; ++r) {
                const int i = i0 + r;
                if (i == 0) {
                    const float mu0 = mu0p[0], ls0 = logstd0p[0];
                    const float inv0 = expf(-ls0);
                    const float2 l0 = ((const float2*)loc)[n * TT];
                    const float dx = (l0.x - mu0) * inv0;
                    const float dy = (l0.y - mu0) * inv0;
                    out[n * TT] = -0.5f * (dx * dx + dy * dy) - (2.0f * ls0 + LOG2PI);
                } else {
                    out[n * TT + i] = Cp + __logf(s1[r]) - __logf(s2[r]);
                }
            }
        }
    }
}

extern "C" void kernel_launch(void* const* d_in, const int* in_sizes, int n_in,
                              void* d_out, int out_size, void* d_ws, size_t ws_size,
                              hipStream_t stream) {
    const float* time_   = (const float*)d_in[0];  // (N,T,1)
    const float* loc     = (const float*)d_in[1];  // (N,T,2)
    // d_in[2] = input_mag, d_in[3] = input_timediff -> unused by reference
    const float* mu0     = (const float*)d_in[4];
    const float* logstd0 = (const float*)d_in[5];
    const float* cd      = (const float*)d_in[6];
    const float* sls     = (const float*)d_in[7];
    float* out = (float*)d_out;                    // (N,T) fp32

    dim3 grid(NN * PAIRS);
    gmsm_kernel<<<grid, 256, 0, stream>>>(time_, loc, mu0, logstd0, cd, sls, out);
}